// Round 1
// 30557.681 us; speedup vs baseline: 3.0618x; 3.0618x over previous
//
#include <hip/hip_runtime.h>
#include <math.h>

#define BATCH 16
#define TLEN 4096
#define KDIM 512
#define G3 1536

// recurrence partition
#define UB 32            // unit-group blocks (16 units each)
#define BB 4             // batch-group blocks (4 batches each)
#define NBLK (UB * BB)   // 128 persistent blocks
#define UPB 16           // units per block
#define BPB 4            // batches per block
#define ROWS 48          // 3 gates * UPB
#define REC_THREADS 384  // 12 tiles * 32 k-splits

#define WP 516           // w_s row pitch (floats)
#define HP 516           // h_s row pitch
#define PP 36            // partials row pitch (32 + 4, float4-aligned)

#define W_OFF 0
#define H_OFF (ROWS * WP)                    // 24768
#define PART_OFF (H_OFF + BPB * HP)          // 26832
#define GH_OFF (PART_OFF + 12 * 16 * PP)     // 33744
#define XQ_OFF (GH_OFF + ROWS * BPB)         // 33936
#define BH_OFF (XQ_OFF + 3 * BPB * UPB)      // 34128
#define SMEM_FLOATS (BH_OFF + ROWS)          // 34176
#define SMEM_BYTES (SMEM_FLOATS * 4)         // 136704 B (< 160 KiB)

#define FLAG_STRIDE 32   // u32 per flag slot = 128 B (own cacheline per block)

typedef __attribute__((ext_vector_type(4))) float f32x4;

// 16B load that reads from the device point of coherence (bypasses stale L1/L2).
__device__ __forceinline__ f32x4 load_f4_sc(const float* p) {
  f32x4 r;
  asm volatile("global_load_dwordx4 %0, %1, off sc0 sc1"
               : "=v"(r) : "v"(p) : "memory");
  return r;
}

// ---------------------------------------------------------------------------
// GEMM: xp_t = A[M,K] @ W[N,K]^T + bias, written in recurrence-friendly
// transposed layout: xp_t[t][ublock(32)][bblock(4)][gate(3)][b_in(4)][u_in(16)]
// so each rec block reads one contiguous 768B slice per step.
// ---------------------------------------------------------------------------
__global__ __launch_bounds__(256)
void gemm_nt_bias(const float* __restrict__ A, const float* __restrict__ W,
                  const float* __restrict__ bias, float* __restrict__ C,
                  int M, int N) {
  const int K = KDIM;
  __shared__ float As[16][132];
  __shared__ float Bs[16][132];
  int tid = threadIdx.x;
  int tx = tid & 15, ty = tid >> 4;
  int bx = blockIdx.x, by = blockIdx.y;
  const float* Ab = A + (size_t)by * 128 * K;
  const float* Wb = W + (size_t)bx * 128 * K;

  float acc[8][8];
#pragma unroll
  for (int i = 0; i < 8; i++)
#pragma unroll
    for (int j = 0; j < 8; j++) acc[i][j] = 0.f;

  for (int kk = 0; kk < K; kk += 16) {
    __syncthreads();
#pragma unroll
    for (int i = 0; i < 2; i++) {
      int task = tid + i * 256;
      int kc = task & 3;
      int m = task >> 2;
      float4 va = *(const float4*)(Ab + (size_t)m * K + kk + kc * 4);
      As[kc*4+0][m] = va.x; As[kc*4+1][m] = va.y;
      As[kc*4+2][m] = va.z; As[kc*4+3][m] = va.w;
      float4 vb = *(const float4*)(Wb + (size_t)m * K + kk + kc * 4);
      Bs[kc*4+0][m] = vb.x; Bs[kc*4+1][m] = vb.y;
      Bs[kc*4+2][m] = vb.z; Bs[kc*4+3][m] = vb.w;
    }
    __syncthreads();
#pragma unroll
    for (int k = 0; k < 16; k++) {
      float4 a0 = *(const float4*)&As[k][ty * 4];
      float4 a1 = *(const float4*)&As[k][64 + ty * 4];
      float4 b0 = *(const float4*)&Bs[k][tx * 4];
      float4 b1 = *(const float4*)&Bs[k][64 + tx * 4];
      float av[8] = {a0.x, a0.y, a0.z, a0.w, a1.x, a1.y, a1.z, a1.w};
      float bv[8] = {b0.x, b0.y, b0.z, b0.w, b1.x, b1.y, b1.z, b1.w};
#pragma unroll
      for (int i = 0; i < 8; i++)
#pragma unroll
        for (int j = 0; j < 8; j++) acc[i][j] += av[i] * bv[j];
    }
  }

#pragma unroll
  for (int hi = 0; hi < 2; hi++)
#pragma unroll
    for (int i = 0; i < 4; i++) {
      int m = by * 128 + hi * 64 + ty * 4 + i;
      int b = m >> 12;           // m / TLEN
      int t = m & (TLEN - 1);
#pragma unroll
      for (int hj = 0; hj < 2; hj++) {
        int n = bx * 128 + hj * 64 + tx * 4;
        int g = n >> 9;          // gate
        int unit = n & 511;
        float4 bb = *(const float4*)(bias + n);
        float4 v;
        v.x = acc[hi*4+i][hj*4+0] + bb.x;
        v.y = acc[hi*4+i][hj*4+1] + bb.y;
        v.z = acc[hi*4+i][hj*4+2] + bb.z;
        v.w = acc[hi*4+i][hj*4+3] + bb.w;
        // xp_t[t][unit>>4][b>>2][g][b&3][unit&15]
        size_t dst = ((((size_t)t * UB + (unit >> 4)) * BB + (b >> 2)) * 3 + g) * (BPB * UPB)
                     + (b & 3) * UPB + (unit & 15);
        *(float4*)(C + dst) = v;
      }
    }
}

// ---------------------------------------------------------------------------
// Persistent GRU recurrence. Grid (32 ublocks, 4 bblocks) = 128 blocks,
// 384 threads, 136.7 KB dynamic LDS, 1 block/CU, all co-resident.
//
// Inter-block sync: per-batch-group distributed flags (no central atomic, no
// agent fences). h values go through the point of coherence via sc0/sc1
// stores/loads; each block publishes flag = flag_base + t + 1 on its own
// 128B line after a vmcnt drain; consumers poll the 32 flags of their group.
// ---------------------------------------------------------------------------
__global__ __launch_bounds__(REC_THREADS, 1)
void gru_rec(const float* __restrict__ xp,     // transposed layout (see gemm)
             const float* __restrict__ w_hh,   // [1536,512]
             const float* __restrict__ b_hh,   // [1536]
             float* __restrict__ hbuf,         // [2][16][512]
             unsigned* __restrict__ flags,     // [NBLK] spaced FLAG_STRIDE u32
             unsigned flag_base,               // 0 for layer1, TLEN for layer2
             float* __restrict__ out,          // [B,T,512]
             int apply_gelu) {
  extern __shared__ float sm[];
  float* w_s   = sm + W_OFF;     // [48][WP]
  float* h_s   = sm + H_OFF;     // [4][HP]  full h(t-1) for this block's batches
  float* part_s= sm + PART_OFF;  // [12*16][PP]
  float* gh_s  = sm + GH_OFF;    // [48*4]  (r*4+b)
  float* xq_s  = sm + XQ_OFF;    // [3][4][16] = [g][b][u]
  float* bhh_s = sm + BH_OFF;    // [48]

  const int tid = threadIdx.x;
  const int u0 = blockIdx.x * UPB;
  const int b0 = blockIdx.y * BPB;
  const float* xslice = xp + ((size_t)blockIdx.x * BB + blockIdx.y) * (3 * BPB * UPB);

  const unsigned* gflags = flags + (size_t)blockIdx.y * UB * FLAG_STRIDE;
  unsigned* myflag = flags + ((size_t)blockIdx.y * UB + blockIdx.x) * FLAG_STRIDE;

  // ---- stage w rows: r = gate*16+u  <->  global row gate*512+u0+u ----
  for (int idx = tid; idx < ROWS * 128; idx += REC_THREADS) {
    int r = idx >> 7, k4 = idx & 127;
    int gate = r >> 4, u = r & 15;
    float4 v = *(const float4*)(w_hh + (size_t)(gate * KDIM + u0 + u) * KDIM + k4 * 4);
    *(float4*)(w_s + r * WP + k4 * 4) = v;
  }
  if (tid < ROWS) bhh_s[tid] = b_hh[(tid >> 4) * KDIM + u0 + (tid & 15)];

  // prefetch x-slice for t=0 (one contiguous 768B chunk, 48 float4)
  float4 xq_reg = {0.f, 0.f, 0.f, 0.f};
  if (tid < 48) xq_reg = *(const float4*)(xslice + tid * 4);
  __syncthreads();

  const int tile = tid >> 5;   // 0..11 (4-row tiles)
  const int ks = tid & 31;     // k-split lane

  for (int t = 0; t < TLEN; t++) {
    // ---- wait for peers' h(t-1), then stage it [4 batches x 512] ----
    if (t == 0) {
      for (int idx = tid; idx < BPB * KDIM; idx += REC_THREADS)
        h_s[(idx >> 9) * HP + (idx & 511)] = 0.f;
    } else {
      // poll my group's 32 flags (one wave; others fall through to barrier)
      if (tid < 64) {
        const unsigned* fp = gflags + (size_t)(tid & 31) * FLAG_STRIDE;
        const unsigned tgt = flag_base + (unsigned)t;
        while (__hip_atomic_load(fp, __ATOMIC_RELAXED, __HIP_MEMORY_SCOPE_AGENT) < tgt)
          __builtin_amdgcn_s_sleep(1);
      }
      __syncthreads();
      // coherent 16B loads of h(t-1): 512 chunks, threads 0..383 + 0..127
      const float* hr = hbuf + (size_t)((t + 1) & 1) * (BATCH * KDIM);
      int b = tid >> 7, k4 = tid & 127;
      f32x4 v0 = load_f4_sc(hr + (size_t)(b0 + b) * KDIM + k4 * 4);
      f32x4 v1 = {0.f, 0.f, 0.f, 0.f};
      if (tid < 128) {
        int c1 = tid + REC_THREADS;
        int b1 = c1 >> 7, k41 = c1 & 127;
        v1 = load_f4_sc(hr + (size_t)(b0 + b1) * KDIM + k41 * 4);
      }
      asm volatile("s_waitcnt vmcnt(0)" ::: "memory");
      *(f32x4*)(h_s + b * HP + k4 * 4) = v0;
      if (tid < 128) {
        int c1 = tid + REC_THREADS;
        int b1 = c1 >> 7, k41 = c1 & 127;
        *(f32x4*)(h_s + b1 * HP + k41 * 4) = v1;
      }
    }
    // publish this step's x-slice from the prefetch register
    if (tid < 48) *(float4*)(xq_s + tid * 4) = xq_reg;
    __syncthreads();

    // issue prefetch for t+1 (completes well before it's consumed next iter)
    if (tid < 48 && t + 1 < TLEN)
      xq_reg = *(const float4*)(xslice + (size_t)(t + 1) * (UB * BB * 3 * BPB * UPB) + tid * 4);

    // ---- dots: 4 rows x 4 batches per thread, k-interleaved split ----
    float4 a00={0,0,0,0},a01={0,0,0,0},a02={0,0,0,0},a03={0,0,0,0};
    float4 a10={0,0,0,0},a11={0,0,0,0},a12={0,0,0,0},a13={0,0,0,0};
    float4 a20={0,0,0,0},a21={0,0,0,0},a22={0,0,0,0},a23={0,0,0,0};
    float4 a30={0,0,0,0},a31={0,0,0,0},a32={0,0,0,0},a33={0,0,0,0};
#pragma unroll
    for (int kk = 0; kk < 4; kk++) {
      int k4 = kk * 32 + ks;           // float4 index, lane-consecutive
      float4 h0v = *(const float4*)(h_s + 0 * HP + k4 * 4);
      float4 h1v = *(const float4*)(h_s + 1 * HP + k4 * 4);
      float4 h2v = *(const float4*)(h_s + 2 * HP + k4 * 4);
      float4 h3v = *(const float4*)(h_s + 3 * HP + k4 * 4);
      float4 w0v = *(const float4*)(w_s + (tile * 4 + 0) * WP + k4 * 4);
      float4 w1v = *(const float4*)(w_s + (tile * 4 + 1) * WP + k4 * 4);
      float4 w2v = *(const float4*)(w_s + (tile * 4 + 2) * WP + k4 * 4);
      float4 w3v = *(const float4*)(w_s + (tile * 4 + 3) * WP + k4 * 4);
#define FMA4(d, wv, hv) d.x += wv.x*hv.x; d.y += wv.y*hv.y; d.z += wv.z*hv.z; d.w += wv.w*hv.w;
      FMA4(a00, w0v, h0v) FMA4(a01, w0v, h1v) FMA4(a02, w0v, h2v) FMA4(a03, w0v, h3v)
      FMA4(a10, w1v, h0v) FMA4(a11, w1v, h1v) FMA4(a12, w1v, h2v) FMA4(a13, w1v, h3v)
      FMA4(a20, w2v, h0v) FMA4(a21, w2v, h1v) FMA4(a22, w2v, h2v) FMA4(a23, w2v, h3v)
      FMA4(a30, w3v, h0v) FMA4(a31, w3v, h1v) FMA4(a32, w3v, h2v) FMA4(a33, w3v, h3v)
#undef FMA4
    }
    {
      float* pb = part_s + (size_t)tile * 16 * PP + ks;
#define HS(v) ((v.x + v.y) + (v.z + v.w))
      pb[(0*4+0)*PP] = HS(a00); pb[(0*4+1)*PP] = HS(a01); pb[(0*4+2)*PP] = HS(a02); pb[(0*4+3)*PP] = HS(a03);
      pb[(1*4+0)*PP] = HS(a10); pb[(1*4+1)*PP] = HS(a11); pb[(1*4+2)*PP] = HS(a12); pb[(1*4+3)*PP] = HS(a13);
      pb[(2*4+0)*PP] = HS(a20); pb[(2*4+1)*PP] = HS(a21); pb[(2*4+2)*PP] = HS(a22); pb[(2*4+3)*PP] = HS(a23);
      pb[(3*4+0)*PP] = HS(a30); pb[(3*4+1)*PP] = HS(a31); pb[(3*4+2)*PP] = HS(a32); pb[(3*4+3)*PP] = HS(a33);
#undef HS
    }
    __syncthreads();

    // ---- reduce 32 k-split partials -> gh (threads 0..191, p = r*4+b = tid) ----
    if (tid < 192) {
      const float* p = part_s + (size_t)tid * PP;
      float4 s0 = *(const float4*)(p + 0);
      float4 s1 = *(const float4*)(p + 4);
      float4 s2 = *(const float4*)(p + 8);
      float4 s3 = *(const float4*)(p + 12);
      float4 s4 = *(const float4*)(p + 16);
      float4 s5 = *(const float4*)(p + 20);
      float4 s6 = *(const float4*)(p + 24);
      float4 s7 = *(const float4*)(p + 28);
      float4 ss;
      ss.x = s0.x + s1.x + s2.x + s3.x + s4.x + s5.x + s6.x + s7.x;
      ss.y = s0.y + s1.y + s2.y + s3.y + s4.y + s5.y + s6.y + s7.y;
      ss.z = s0.z + s1.z + s2.z + s3.z + s4.z + s5.z + s6.z + s7.z;
      ss.w = s0.w + s1.w + s2.w + s3.w + s4.w + s5.w + s6.w + s7.w;
      gh_s[tid] = (ss.x + ss.y) + (ss.z + ss.w) + bhh_s[tid >> 2];
    }
    __syncthreads();

    // ---- gates + h update (64 threads: u = tid&15, b = tid>>4) ----
    if (tid < 64) {
      int u = tid & 15, b = tid >> 4;
      float xr = xq_s[0 * 64 + b * 16 + u];
      float xz = xq_s[1 * 64 + b * 16 + u];
      float xn = xq_s[2 * 64 + b * 16 + u];
      float ghr = gh_s[(0 * 16 + u) * 4 + b];
      float ghz = gh_s[(1 * 16 + u) * 4 + b];
      float ghn = gh_s[(2 * 16 + u) * 4 + b];
      float rg = 1.f / (1.f + expf(-(xr + ghr)));
      float zg = 1.f / (1.f + expf(-(xz + ghz)));
      float ng = tanhf(xn + rg * ghn);
      float hold = h_s[b * HP + u0 + u];
      float hn = (1.f - zg) * ng + zg * hold;
      // coherence-point store: visible to all XCDs once vmcnt retires
      __hip_atomic_store(hbuf + (size_t)(t & 1) * (BATCH * KDIM) + (size_t)(b0 + b) * KDIM + u0 + u,
                         hn, __ATOMIC_RELAXED, __HIP_MEMORY_SCOPE_AGENT);
      float ov = hn;
      if (apply_gelu) ov = 0.5f * hn * (1.f + erff(hn * 0.70710678118654752f));
      out[((size_t)((b0 + b) * TLEN + t)) * KDIM + u0 + u] = ov;
    }

    // drain own stores, block-wide rendezvous, then publish arrival flag
    asm volatile("s_waitcnt vmcnt(0)" ::: "memory");
    __syncthreads();   // all threads' h stores have retired at coherence point
    if (tid == 0)
      __hip_atomic_store(myflag, flag_base + (unsigned)t + 1u,
                         __ATOMIC_RELAXED, __HIP_MEMORY_SCOPE_AGENT);
  }
}

// ---------------------------------------------------------------------------
// ws layout: [0, 402.65MB) xp_t | hbuf 64KB | flags 16KB
// ---------------------------------------------------------------------------
extern "C" void kernel_launch(void* const* d_in, const int* in_sizes, int n_in,
                              void* d_out, int out_size, void* d_ws, size_t ws_size,
                              hipStream_t stream) {
  const float* x     = (const float*)d_in[0];
  const float* w_ih1 = (const float*)d_in[1];
  const float* w_hh1 = (const float*)d_in[2];
  const float* b_ih1 = (const float*)d_in[3];
  const float* b_hh1 = (const float*)d_in[4];
  const float* w_ih2 = (const float*)d_in[5];
  const float* w_hh2 = (const float*)d_in[6];
  const float* b_ih2 = (const float*)d_in[7];
  const float* b_hh2 = (const float*)d_in[8];
  float* y = (float*)d_out;

  char* ws = (char*)d_ws;
  const size_t XPB = (size_t)BATCH * TLEN * G3 * sizeof(float);
  float*    xp    = (float*)ws;
  float*    hbuf  = (float*)(ws + XPB);
  unsigned* flags = (unsigned*)(ws + XPB + (size_t)2 * BATCH * KDIM * sizeof(float));

  hipFuncSetAttribute((const void*)gru_rec,
                      hipFuncAttributeMaxDynamicSharedMemorySize, SMEM_BYTES);
  hipMemsetAsync(flags, 0, NBLK * FLAG_STRIDE * sizeof(unsigned), stream);

  dim3 gg(12, 512), tb(256);
  const int M = BATCH * TLEN;

  gemm_nt_bias<<<gg, tb, 0, stream>>>(x, w_ih1, b_ih1, xp, M, G3);
  gru_rec<<<dim3(UB, BB), REC_THREADS, SMEM_BYTES, stream>>>(xp, w_hh1, b_hh1, hbuf, flags, 0u, y, 1);
  gemm_nt_bias<<<gg, tb, 0, stream>>>(y, w_ih2, b_ih2, xp, M, G3);
  gru_rec<<<dim3(UB, BB), REC_THREADS, SMEM_BYTES, stream>>>(xp, w_hh2, b_hh2, hbuf, flags, (unsigned)TLEN, y, 0);
}

// Round 2
// 29116.626 us; speedup vs baseline: 3.2133x; 1.0495x over previous
//
#include <hip/hip_runtime.h>
#include <math.h>

#define BATCH 16
#define TLEN 4096
#define KDIM 512
#define G3 1536

// recurrence partition
#define UB 32            // unit-group blocks (16 units each)
#define BB 4             // batch-group blocks (4 batches each)
#define NBLK (UB * BB)   // 128 persistent blocks
#define UPB 16           // units per block
#define BPB 4            // batches per block
#define ROWS 48          // 3 gates * UPB
#define REC_THREADS 384  // 12 tiles * 32 k-splits

#define HP 516           // h_s row pitch
#define PP 36            // partials row pitch (32 + 4, float4-aligned)

// LDS layout (w_hh now lives in registers — 37.6 KB total)
#define H_OFF 0
#define PART_OFF (BPB * HP)                  // 2064
#define GH_OFF (PART_OFF + 12 * 16 * PP)     // 8976
#define XQ_OFF (GH_OFF + ROWS * BPB)         // 9168
#define BH_OFF (XQ_OFF + 3 * BPB * UPB)      // 9360
#define SMEM_FLOATS (BH_OFF + ROWS)          // 9408
#define SMEM_BYTES (SMEM_FLOATS * 4)         // 37632 B

#define FLAG_STRIDE 32   // u32 per flag slot = 128 B (own cacheline per block)

typedef __attribute__((ext_vector_type(4))) float f32x4;

// 16B load that reads from the device point of coherence (bypasses stale L1/L2).
__device__ __forceinline__ f32x4 load_f4_sc(const float* p) {
  f32x4 r;
  asm volatile("global_load_dwordx4 %0, %1, off sc0 sc1"
               : "=v"(r) : "v"(p) : "memory");
  return r;
}

__device__ __forceinline__ float fast_sigmoid(float x) {
  float e = __expf(-x);
  return __builtin_amdgcn_rcpf(1.f + e);
}
__device__ __forceinline__ float fast_tanh(float x) {
  float ax = fabsf(x);
  float e = __expf(-2.f * ax);
  float r = (1.f - e) * __builtin_amdgcn_rcpf(1.f + e);
  return copysignf(r, x);
}

// ---------------------------------------------------------------------------
// GEMM: xp_t = A[M,K] @ W[N,K]^T + bias, written in recurrence-friendly
// transposed layout: xp_t[t][ublock(32)][bblock(4)][gate(3)][b_in(4)][u_in(16)]
// so each rec block reads one contiguous 768B slice per step.
// ---------------------------------------------------------------------------
__global__ __launch_bounds__(256)
void gemm_nt_bias(const float* __restrict__ A, const float* __restrict__ W,
                  const float* __restrict__ bias, float* __restrict__ C,
                  int M, int N) {
  const int K = KDIM;
  __shared__ float As[16][132];
  __shared__ float Bs[16][132];
  int tid = threadIdx.x;
  int tx = tid & 15, ty = tid >> 4;
  int bx = blockIdx.x, by = blockIdx.y;
  const float* Ab = A + (size_t)by * 128 * K;
  const float* Wb = W + (size_t)bx * 128 * K;

  float acc[8][8];
#pragma unroll
  for (int i = 0; i < 8; i++)
#pragma unroll
    for (int j = 0; j < 8; j++) acc[i][j] = 0.f;

  for (int kk = 0; kk < K; kk += 16) {
    __syncthreads();
#pragma unroll
    for (int i = 0; i < 2; i++) {
      int task = tid + i * 256;
      int kc = task & 3;
      int m = task >> 2;
      float4 va = *(const float4*)(Ab + (size_t)m * K + kk + kc * 4);
      As[kc*4+0][m] = va.x; As[kc*4+1][m] = va.y;
      As[kc*4+2][m] = va.z; As[kc*4+3][m] = va.w;
      float4 vb = *(const float4*)(Wb + (size_t)m * K + kk + kc * 4);
      Bs[kc*4+0][m] = vb.x; Bs[kc*4+1][m] = vb.y;
      Bs[kc*4+2][m] = vb.z; Bs[kc*4+3][m] = vb.w;
    }
    __syncthreads();
#pragma unroll
    for (int k = 0; k < 16; k++) {
      float4 a0 = *(const float4*)&As[k][ty * 4];
      float4 a1 = *(const float4*)&As[k][64 + ty * 4];
      float4 b0 = *(const float4*)&Bs[k][tx * 4];
      float4 b1 = *(const float4*)&Bs[k][64 + tx * 4];
      float av[8] = {a0.x, a0.y, a0.z, a0.w, a1.x, a1.y, a1.z, a1.w};
      float bv[8] = {b0.x, b0.y, b0.z, b0.w, b1.x, b1.y, b1.z, b1.w};
#pragma unroll
      for (int i = 0; i < 8; i++)
#pragma unroll
        for (int j = 0; j < 8; j++) acc[i][j] += av[i] * bv[j];
    }
  }

#pragma unroll
  for (int hi = 0; hi < 2; hi++)
#pragma unroll
    for (int i = 0; i < 4; i++) {
      int m = by * 128 + hi * 64 + ty * 4 + i;
      int b = m >> 12;           // m / TLEN
      int t = m & (TLEN - 1);
#pragma unroll
      for (int hj = 0; hj < 2; hj++) {
        int n = bx * 128 + hj * 64 + tx * 4;
        int g = n >> 9;          // gate
        int unit = n & 511;
        float4 bb = *(const float4*)(bias + n);
        float4 v;
        v.x = acc[hi*4+i][hj*4+0] + bb.x;
        v.y = acc[hi*4+i][hj*4+1] + bb.y;
        v.z = acc[hi*4+i][hj*4+2] + bb.z;
        v.w = acc[hi*4+i][hj*4+3] + bb.w;
        // xp_t[t][unit>>4][b>>2][g][b&3][unit&15]
        size_t dst = ((((size_t)t * UB + (unit >> 4)) * BB + (b >> 2)) * 3 + g) * (BPB * UPB)
                     + (b & 3) * UPB + (unit & 15);
        *(float4*)(C + dst) = v;
      }
    }
}

// ---------------------------------------------------------------------------
// Persistent GRU recurrence. Grid (32 ublocks, 4 bblocks) = 128 blocks,
// 384 threads, 37.6 KB dynamic LDS, 1 block/CU, all co-resident.
//
// w_hh is register-resident: each thread holds its 4 rows x 16-float k-chunk
// (16 float4 = 64 VGPRs), loaded once before the time loop. The per-step dot
// phase reads only h from LDS (halved LDS traffic vs LDS-staged w).
//
// Inter-block sync: per-batch-group distributed flags (no central atomic, no
// agent fences). h values go through the point of coherence via sc0/sc1
// stores/loads; each block publishes flag = flag_base + t + 1 on its own
// 128B line after a vmcnt drain; consumers poll the 32 flags of their group.
// GELU + out-store are issued AFTER the flag publish (off the critical path).
// ---------------------------------------------------------------------------
__global__ __launch_bounds__(REC_THREADS, 1)
void gru_rec(const float* __restrict__ xp,     // transposed layout (see gemm)
             const float* __restrict__ w_hh,   // [1536,512]
             const float* __restrict__ b_hh,   // [1536]
             float* __restrict__ hbuf,         // [2][16][512]
             unsigned* __restrict__ flags,     // [NBLK] spaced FLAG_STRIDE u32
             unsigned flag_base,               // 0 for layer1, TLEN for layer2
             float* __restrict__ out,          // [B,T,512]
             int apply_gelu) {
  extern __shared__ float sm[];
  float* h_s   = sm + H_OFF;     // [4][HP]  full h(t-1) for this block's batches
  float* part_s= sm + PART_OFF;  // [12*16][PP]
  float* gh_s  = sm + GH_OFF;    // [48*4]  (r*4+b)
  float* xq_s  = sm + XQ_OFF;    // [3][4][16] = [g][b][u]
  float* bhh_s = sm + BH_OFF;    // [48]

  const int tid = threadIdx.x;
  const int u0 = blockIdx.x * UPB;
  const int b0 = blockIdx.y * BPB;
  const float* xslice = xp + ((size_t)blockIdx.x * BB + blockIdx.y) * (3 * BPB * UPB);

  const unsigned* gflags = flags + (size_t)blockIdx.y * UB * FLAG_STRIDE;
  unsigned* myflag = flags + ((size_t)blockIdx.y * UB + blockIdx.x) * FLAG_STRIDE;

  const int tile = tid >> 5;   // 0..11 (4-row tiles)
  const int ks = tid & 31;     // k-split lane

  // ---- load this thread's w slice into registers: 4 rows x 4 f32x4 (k-interleaved) ----
  float4 wreg[4][4];
#pragma unroll
  for (int r = 0; r < 4; r++) {
    int row = tile * 4 + r;                  // 0..47 == gate*16 + u
    int gate = row >> 4, u = row & 15;
    const float* wrow = w_hh + (size_t)(gate * KDIM + u0 + u) * KDIM;
#pragma unroll
    for (int kk = 0; kk < 4; kk++)
      wreg[r][kk] = *(const float4*)(wrow + (size_t)(kk * 32 + ks) * 4);
  }
  if (tid < ROWS) bhh_s[tid] = b_hh[(tid >> 4) * KDIM + u0 + (tid & 15)];

  // prefetch x-slice for t=0 (one contiguous 768B chunk, 48 float4)
  float4 xq_reg = {0.f, 0.f, 0.f, 0.f};
  if (tid < 48) xq_reg = *(const float4*)(xslice + tid * 4);
  __syncthreads();

  for (int t = 0; t < TLEN; t++) {
    // ---- wait for peers' h(t-1), then stage it [4 batches x 512] ----
    if (t == 0) {
      for (int idx = tid; idx < BPB * KDIM; idx += REC_THREADS)
        h_s[(idx >> 9) * HP + (idx & 511)] = 0.f;
    } else {
      // poll my group's 32 flags (one wave; others fall through to barrier)
      if (tid < 64) {
        const unsigned* fp = gflags + (size_t)(tid & 31) * FLAG_STRIDE;
        const unsigned tgt = flag_base + (unsigned)t;
        while (__hip_atomic_load(fp, __ATOMIC_RELAXED, __HIP_MEMORY_SCOPE_AGENT) < tgt)
          __builtin_amdgcn_s_sleep(1);
      }
      __syncthreads();
      // coherent 16B loads of h(t-1): 512 chunks, threads 0..383 + 0..127
      const float* hr = hbuf + (size_t)((t + 1) & 1) * (BATCH * KDIM);
      int b = tid >> 7, k4 = tid & 127;
      f32x4 v0 = load_f4_sc(hr + (size_t)(b0 + b) * KDIM + k4 * 4);
      f32x4 v1 = {0.f, 0.f, 0.f, 0.f};
      if (tid < 128) {
        int c1 = tid + REC_THREADS;
        int b1 = c1 >> 7, k41 = c1 & 127;
        v1 = load_f4_sc(hr + (size_t)(b0 + b1) * KDIM + k41 * 4);
      }
      asm volatile("s_waitcnt vmcnt(0)" ::: "memory");
      *(f32x4*)(h_s + b * HP + k4 * 4) = v0;
      if (tid < 128) {
        int c1 = tid + REC_THREADS;
        int b1 = c1 >> 7, k41 = c1 & 127;
        *(f32x4*)(h_s + b1 * HP + k41 * 4) = v1;
      }
    }
    // publish this step's x-slice from the prefetch register
    if (tid < 48) *(float4*)(xq_s + tid * 4) = xq_reg;
    __syncthreads();

    // issue prefetch for t+1 (completes well before it's consumed next iter)
    if (tid < 48 && t + 1 < TLEN)
      xq_reg = *(const float4*)(xslice + (size_t)(t + 1) * (UB * BB * 3 * BPB * UPB) + tid * 4);

    // ---- dots: 4 rows x 4 batches per thread, w in registers, h from LDS ----
    float4 a00={0,0,0,0},a01={0,0,0,0},a02={0,0,0,0},a03={0,0,0,0};
    float4 a10={0,0,0,0},a11={0,0,0,0},a12={0,0,0,0},a13={0,0,0,0};
    float4 a20={0,0,0,0},a21={0,0,0,0},a22={0,0,0,0},a23={0,0,0,0};
    float4 a30={0,0,0,0},a31={0,0,0,0},a32={0,0,0,0},a33={0,0,0,0};
#pragma unroll
    for (int kk = 0; kk < 4; kk++) {
      int k4 = kk * 32 + ks;           // float4 index, lane-consecutive
      float4 h0v = *(const float4*)(h_s + 0 * HP + k4 * 4);
      float4 h1v = *(const float4*)(h_s + 1 * HP + k4 * 4);
      float4 h2v = *(const float4*)(h_s + 2 * HP + k4 * 4);
      float4 h3v = *(const float4*)(h_s + 3 * HP + k4 * 4);
#define FMA4(d, wv, hv) d.x += wv.x*hv.x; d.y += wv.y*hv.y; d.z += wv.z*hv.z; d.w += wv.w*hv.w;
      FMA4(a00, wreg[0][kk], h0v) FMA4(a01, wreg[0][kk], h1v) FMA4(a02, wreg[0][kk], h2v) FMA4(a03, wreg[0][kk], h3v)
      FMA4(a10, wreg[1][kk], h0v) FMA4(a11, wreg[1][kk], h1v) FMA4(a12, wreg[1][kk], h2v) FMA4(a13, wreg[1][kk], h3v)
      FMA4(a20, wreg[2][kk], h0v) FMA4(a21, wreg[2][kk], h1v) FMA4(a22, wreg[2][kk], h2v) FMA4(a23, wreg[2][kk], h3v)
      FMA4(a30, wreg[3][kk], h0v) FMA4(a31, wreg[3][kk], h1v) FMA4(a32, wreg[3][kk], h2v) FMA4(a33, wreg[3][kk], h3v)
#undef FMA4
    }
    {
      float* pb = part_s + (size_t)tile * 16 * PP + ks;
#define HS(v) ((v.x + v.y) + (v.z + v.w))
      pb[(0*4+0)*PP] = HS(a00); pb[(0*4+1)*PP] = HS(a01); pb[(0*4+2)*PP] = HS(a02); pb[(0*4+3)*PP] = HS(a03);
      pb[(1*4+0)*PP] = HS(a10); pb[(1*4+1)*PP] = HS(a11); pb[(1*4+2)*PP] = HS(a12); pb[(1*4+3)*PP] = HS(a13);
      pb[(2*4+0)*PP] = HS(a20); pb[(2*4+1)*PP] = HS(a21); pb[(2*4+2)*PP] = HS(a22); pb[(2*4+3)*PP] = HS(a23);
      pb[(3*4+0)*PP] = HS(a30); pb[(3*4+1)*PP] = HS(a31); pb[(3*4+2)*PP] = HS(a32); pb[(3*4+3)*PP] = HS(a33);
#undef HS
    }
    __syncthreads();

    // ---- reduce 32 k-split partials -> gh (threads 0..191, p = r*4+b = tid) ----
    if (tid < 192) {
      const float* p = part_s + (size_t)tid * PP;
      float4 s0 = *(const float4*)(p + 0);
      float4 s1 = *(const float4*)(p + 4);
      float4 s2 = *(const float4*)(p + 8);
      float4 s3 = *(const float4*)(p + 12);
      float4 s4 = *(const float4*)(p + 16);
      float4 s5 = *(const float4*)(p + 20);
      float4 s6 = *(const float4*)(p + 24);
      float4 s7 = *(const float4*)(p + 28);
      float4 ss;
      ss.x = s0.x + s1.x + s2.x + s3.x + s4.x + s5.x + s6.x + s7.x;
      ss.y = s0.y + s1.y + s2.y + s3.y + s4.y + s5.y + s6.y + s7.y;
      ss.z = s0.z + s1.z + s2.z + s3.z + s4.z + s5.z + s6.z + s7.z;
      ss.w = s0.w + s1.w + s2.w + s3.w + s4.w + s5.w + s6.w + s7.w;
      gh_s[tid] = (ss.x + ss.y) + (ss.z + ss.w) + bhh_s[tid >> 2];
    }
    __syncthreads();

    // ---- gates + h update (64 threads: u = tid&15, b = tid>>4) ----
    float hn = 0.f;
    if (tid < 64) {
      int u = tid & 15, b = tid >> 4;
      float xr = xq_s[0 * 64 + b * 16 + u];
      float xz = xq_s[1 * 64 + b * 16 + u];
      float xn = xq_s[2 * 64 + b * 16 + u];
      float ghr = gh_s[(0 * 16 + u) * 4 + b];
      float ghz = gh_s[(1 * 16 + u) * 4 + b];
      float ghn = gh_s[(2 * 16 + u) * 4 + b];
      float rg = fast_sigmoid(xr + ghr);
      float zg = fast_sigmoid(xz + ghz);
      float ng = fast_tanh(xn + rg * ghn);
      float hold = h_s[b * HP + u0 + u];
      hn = (1.f - zg) * ng + zg * hold;
      // coherence-point store: visible to all XCDs once vmcnt retires
      __hip_atomic_store(hbuf + (size_t)(t & 1) * (BATCH * KDIM) + (size_t)(b0 + b) * KDIM + u0 + u,
                         hn, __ATOMIC_RELAXED, __HIP_MEMORY_SCOPE_AGENT);
    }

    // drain own stores, block-wide rendezvous, then publish arrival flag
    asm volatile("s_waitcnt vmcnt(0)" ::: "memory");
    __syncthreads();   // all threads' h stores have retired at coherence point
    if (tid == 0)
      __hip_atomic_store(myflag, flag_base + (unsigned)t + 1u,
                         __ATOMIC_RELAXED, __HIP_MEMORY_SCOPE_AGENT);

    // ---- off-critical-path epilogue: GELU + out store ----
    if (tid < 64) {
      int u = tid & 15, b = tid >> 4;
      float ov = hn;
      if (apply_gelu) ov = 0.5f * hn * (1.f + erff(hn * 0.70710678118654752f));
      out[((size_t)((b0 + b) * TLEN + t)) * KDIM + u0 + u] = ov;
    }
  }
}

// ---------------------------------------------------------------------------
// ws layout: [0, 402.65MB) xp_t | hbuf 64KB | flags 16KB
// ---------------------------------------------------------------------------
extern "C" void kernel_launch(void* const* d_in, const int* in_sizes, int n_in,
                              void* d_out, int out_size, void* d_ws, size_t ws_size,
                              hipStream_t stream) {
  const float* x     = (const float*)d_in[0];
  const float* w_ih1 = (const float*)d_in[1];
  const float* w_hh1 = (const float*)d_in[2];
  const float* b_ih1 = (const float*)d_in[3];
  const float* b_hh1 = (const float*)d_in[4];
  const float* w_ih2 = (const float*)d_in[5];
  const float* w_hh2 = (const float*)d_in[6];
  const float* b_ih2 = (const float*)d_in[7];
  const float* b_hh2 = (const float*)d_in[8];
  float* y = (float*)d_out;

  char* ws = (char*)d_ws;
  const size_t XPB = (size_t)BATCH * TLEN * G3 * sizeof(float);
  float*    xp    = (float*)ws;
  float*    hbuf  = (float*)(ws + XPB);
  unsigned* flags = (unsigned*)(ws + XPB + (size_t)2 * BATCH * KDIM * sizeof(float));

  hipFuncSetAttribute((const void*)gru_rec,
                      hipFuncAttributeMaxDynamicSharedMemorySize, SMEM_BYTES);
  hipMemsetAsync(flags, 0, NBLK * FLAG_STRIDE * sizeof(unsigned), stream);

  dim3 gg(12, 512), tb(256);
  const int M = BATCH * TLEN;

  gemm_nt_bias<<<gg, tb, 0, stream>>>(x, w_ih1, b_ih1, xp, M, G3);
  gru_rec<<<dim3(UB, BB), REC_THREADS, SMEM_BYTES, stream>>>(xp, w_hh1, b_hh1, hbuf, flags, 0u, y, 1);
  gemm_nt_bias<<<gg, tb, 0, stream>>>(y, w_ih2, b_ih2, xp, M, G3);
  gru_rec<<<dim3(UB, BB), REC_THREADS, SMEM_BYTES, stream>>>(xp, w_hh2, b_hh2, hbuf, flags, (unsigned)TLEN, y, 0);
}

// Round 4
// 19116.522 us; speedup vs baseline: 4.8943x; 1.5231x over previous
//
#include <hip/hip_runtime.h>
#include <math.h>

#define BATCH 16
#define TLEN 4096
#define KDIM 512
#define G3 1536

// recurrence partition: 8 groups (batch pairs) x 16 member blocks (32 units)
#define UBK 16           // unit-member blocks per group
#define GRP 8            // batch-pair groups
#define NBLK (UBK * GRP) // 128 persistent blocks
#define UPB 32           // units per block
#define BPB 2            // batches per block
#define ROWS 96          // 3 gates * UPB
#define REC_THREADS 768  // 24 tiles * 32 k-splits

#define HP 516           // h_s row pitch
#define PP 37            // partials row pitch (odd -> conflict-free scalar reads)

#define H_OFF 0
#define PART_OFF (BPB * HP)                   // 1032
#define GH_OFF (PART_OFF + 192 * PP)          // 8136
#define XQ_OFF (GH_OFF + 192)                 // 8328
#define BH_OFF (XQ_OFF + 192)                 // 8520
#define SMEM_FLOATS (BH_OFF + ROWS)           // 8616
#define SMEM_BYTES (SMEM_FLOATS * 4)          // 34464 B

typedef __attribute__((ext_vector_type(4))) float f32x4;
typedef __attribute__((ext_vector_type(2))) unsigned u32x2;
typedef __attribute__((ext_vector_type(4))) unsigned u32x4;

__device__ __forceinline__ float fast_sigmoid(float x) {
  float e = __expf(-x);
  return __builtin_amdgcn_rcpf(1.f + e);
}
__device__ __forceinline__ float fast_tanh(float x) {
  float ax = fabsf(x);
  float e = __expf(-2.f * ax);
  float r = (1.f - e) * __builtin_amdgcn_rcpf(1.f + e);
  return copysignf(r, x);
}

// ---------------------------------------------------------------------------
// GEMM: xp_t = A[M,K] @ W[N,K]^T + bias, written in recurrence-friendly
// transposed layout: xp_t[t][member(16)][group(8)][gate(3)][b&1][u&31]
// so each rec block reads one contiguous 768B slice per step.
// ---------------------------------------------------------------------------
__global__ __launch_bounds__(256)
void gemm_nt_bias(const float* __restrict__ A, const float* __restrict__ W,
                  const float* __restrict__ bias, float* __restrict__ C,
                  int M, int N) {
  const int K = KDIM;
  __shared__ float As[16][132];
  __shared__ float Bs[16][132];
  int tid = threadIdx.x;
  int tx = tid & 15, ty = tid >> 4;
  int bx = blockIdx.x, by = blockIdx.y;
  const float* Ab = A + (size_t)by * 128 * K;
  const float* Wb = W + (size_t)bx * 128 * K;

  float acc[8][8];
#pragma unroll
  for (int i = 0; i < 8; i++)
#pragma unroll
    for (int j = 0; j < 8; j++) acc[i][j] = 0.f;

  for (int kk = 0; kk < K; kk += 16) {
    __syncthreads();
#pragma unroll
    for (int i = 0; i < 2; i++) {
      int task = tid + i * 256;
      int kc = task & 3;
      int mrow = task >> 2;
      float4 va = *(const float4*)(Ab + (size_t)mrow * K + kk + kc * 4);
      As[kc*4+0][mrow] = va.x; As[kc*4+1][mrow] = va.y;
      As[kc*4+2][mrow] = va.z; As[kc*4+3][mrow] = va.w;
      float4 vb = *(const float4*)(Wb + (size_t)mrow * K + kk + kc * 4);
      Bs[kc*4+0][mrow] = vb.x; Bs[kc*4+1][mrow] = vb.y;
      Bs[kc*4+2][mrow] = vb.z; Bs[kc*4+3][mrow] = vb.w;
    }
    __syncthreads();
#pragma unroll
    for (int k = 0; k < 16; k++) {
      float4 a0 = *(const float4*)&As[k][ty * 4];
      float4 a1 = *(const float4*)&As[k][64 + ty * 4];
      float4 b0 = *(const float4*)&Bs[k][tx * 4];
      float4 b1 = *(const float4*)&Bs[k][64 + tx * 4];
      float av[8] = {a0.x, a0.y, a0.z, a0.w, a1.x, a1.y, a1.z, a1.w};
      float bv[8] = {b0.x, b0.y, b0.z, b0.w, b1.x, b1.y, b1.z, b1.w};
#pragma unroll
      for (int i = 0; i < 8; i++)
#pragma unroll
        for (int j = 0; j < 8; j++) acc[i][j] += av[i] * bv[j];
    }
  }

#pragma unroll
  for (int hi = 0; hi < 2; hi++)
#pragma unroll
    for (int i = 0; i < 4; i++) {
      int mrow = by * 128 + hi * 64 + ty * 4 + i;
      int b = mrow >> 12;        // m / TLEN
      int t = mrow & (TLEN - 1);
#pragma unroll
      for (int hj = 0; hj < 2; hj++) {
        int n = bx * 128 + hj * 64 + tx * 4;
        int g = n >> 9;          // gate
        int unit = n & 511;
        float4 bb = *(const float4*)(bias + n);
        float4 v;
        v.x = acc[hi*4+i][hj*4+0] + bb.x;
        v.y = acc[hi*4+i][hj*4+1] + bb.y;
        v.z = acc[hi*4+i][hj*4+2] + bb.z;
        v.w = acc[hi*4+i][hj*4+3] + bb.w;
        // xp_t[t][unit>>5][b>>1][g][b&1][unit&31]
        size_t dst = (((((size_t)t * UBK + (unit >> 5)) * GRP + (b >> 1)) * 3 + g) * BPB
                      + (b & 1)) * UPB + (unit & 31);
        *(float4*)(C + dst) = v;
      }
    }
}

// ---------------------------------------------------------------------------
// Persistent GRU recurrence. 128 blocks (8 batch-pair groups x 16 members),
// 768 threads, 34.5 KB LDS, 1 block/CU, all co-resident.
//
// Sync protocol: fused (value,tag) mailbox. Producers store each h element as
// an 8B (float_bits, tag) pair with ONE global_store_dwordx2 sc0 sc1 — no
// drain, no flag publish. Consumers poll the pairs directly (dwordx4 = 2
// pairs/lane) until tag >= flag_base+t; the same registers hold the payload.
// Tags are monotonic (flag_base+t+1) -> no reset; parity-2 buffering is safe
// by step causality. Correct on any block->XCD mapping (device-scope ops).
// ---------------------------------------------------------------------------
__global__ __launch_bounds__(REC_THREADS, 1)
void gru_rec(const float* __restrict__ xp,     // transposed layout (see gemm)
             const float* __restrict__ w_hh,   // [1536,512]
             const float* __restrict__ b_hh,   // [1536]
             unsigned* __restrict__ mb,        // mailbox [2][GRP][UBK*64] pairs
             unsigned flag_base,               // 0 layer1, TLEN layer2
             float* __restrict__ out,          // [B,T,512]
             int apply_gelu) {
  extern __shared__ float sm[];
  float* h_s   = sm + H_OFF;     // [2][HP]
  float* part_s= sm + PART_OFF;  // [192][PP]
  float* gh_s  = sm + GH_OFF;    // [192]  (row*2+b)
  float* xq_s  = sm + XQ_OFF;    // [3][2][32]
  float* bhh_s = sm + BH_OFF;    // [96]

  const int tid = threadIdx.x;
  const int L = blockIdx.x;
  const int g = L & 7;           // group (batch pair)
  const int m = L >> 3;          // member (unit block)
  const int u0 = m * UPB;
  const int b0 = g * BPB;
  const float* xslice = xp + ((size_t)m * GRP + g) * (3 * BPB * UPB);

  const int tile = tid >> 5;   // 0..23 (4-row tiles)
  const int ks = tid & 31;     // k-split lane

  // ---- load this thread's w slice into registers: 4 rows x 4 f32x4 ----
  float4 wreg[4][4];
#pragma unroll
  for (int r = 0; r < 4; r++) {
    int row = tile * 4 + r;                  // 0..95 == gate*32 + u
    int gate = row >> 5, u = row & 31;
    const float* wrow = w_hh + (size_t)(gate * KDIM + u0 + u) * KDIM;
#pragma unroll
    for (int kk = 0; kk < 4; kk++)
      wreg[r][kk] = *(const float4*)(wrow + (size_t)(kk * 32 + ks) * 4);
  }
  if (tid < ROWS) bhh_s[tid] = b_hh[(tid >> 5) * KDIM + u0 + (tid & 31)];

  // prefetch x-slice for t=0 (one contiguous 768B chunk, 48 float4)
  float4 xq_reg = {0.f, 0.f, 0.f, 0.f};
  if (tid < 48) xq_reg = *(const float4*)(xslice + tid * 4);

  float hprev = 0.f;   // gate thread's own h(t-1)[b][u0+u]

  for (int t = 0; t < TLEN; t++) {
    // ---- stage h(t-1): poll mailbox pairs, payload rides with the tag ----
    if (t == 0) {
      for (int idx = tid; idx < BPB * KDIM; idx += REC_THREADS)
        h_s[(idx >> 9) * HP + (idx & 511)] = 0.f;
    } else {
      if (tid < 512) {
        const unsigned* src = mb + ((size_t)(((t + 1) & 1) * GRP + g) * 1024
                                    + (size_t)tid * 2) * 2;
        const unsigned tgt = flag_base + (unsigned)t;
        u32x4 pv;
        for (;;) {
          asm volatile("global_load_dwordx4 %0, %1, off sc0 sc1\n\ts_waitcnt vmcnt(0)"
                       : "=v"(pv) : "v"(src) : "memory");
          if (pv.y >= tgt && pv.w >= tgt) break;
          __builtin_amdgcn_s_sleep(1);
        }
        int j0 = tid * 2;
        int mm = j0 >> 6, bb = (j0 >> 5) & 1, uu = j0 & 31;
        float2 hv;
        hv.x = __uint_as_float(pv.x);
        hv.y = __uint_as_float(pv.z);
        *(float2*)(h_s + bb * HP + mm * 32 + uu) = hv;
      }
    }
    // publish this step's x-slice from the prefetch register
    if (tid < 48) *(float4*)(xq_s + tid * 4) = xq_reg;
    __syncthreads();

    // issue prefetch for t+1 (completes well before it's consumed next iter)
    if (tid < 48 && t + 1 < TLEN)
      xq_reg = *(const float4*)(xslice + (size_t)(t + 1) * (UBK * GRP * 3 * BPB * UPB) + tid * 4);

    // ---- dots: 4 rows x 2 batches per thread, w in registers, h from LDS ----
    float4 a00={0,0,0,0},a01={0,0,0,0};
    float4 a10={0,0,0,0},a11={0,0,0,0};
    float4 a20={0,0,0,0},a21={0,0,0,0};
    float4 a30={0,0,0,0},a31={0,0,0,0};
#pragma unroll
    for (int kk = 0; kk < 4; kk++) {
      int k4 = kk * 32 + ks;
      float4 h0v = *(const float4*)(h_s + 0 * HP + k4 * 4);
      float4 h1v = *(const float4*)(h_s + 1 * HP + k4 * 4);
#define FMA4(d, wv, hv) d.x += wv.x*hv.x; d.y += wv.y*hv.y; d.z += wv.z*hv.z; d.w += wv.w*hv.w;
      FMA4(a00, wreg[0][kk], h0v) FMA4(a01, wreg[0][kk], h1v)
      FMA4(a10, wreg[1][kk], h0v) FMA4(a11, wreg[1][kk], h1v)
      FMA4(a20, wreg[2][kk], h0v) FMA4(a21, wreg[2][kk], h1v)
      FMA4(a30, wreg[3][kk], h0v) FMA4(a31, wreg[3][kk], h1v)
#undef FMA4
    }
    {
      float* pb = part_s + (size_t)(tile * 8) * PP + ks;  // partial idx = row*2+b
#define HS(v) ((v.x + v.y) + (v.z + v.w))
      pb[(0*2+0)*PP] = HS(a00); pb[(0*2+1)*PP] = HS(a01);
      pb[(1*2+0)*PP] = HS(a10); pb[(1*2+1)*PP] = HS(a11);
      pb[(2*2+0)*PP] = HS(a20); pb[(2*2+1)*PP] = HS(a21);
      pb[(3*2+0)*PP] = HS(a30); pb[(3*2+1)*PP] = HS(a31);
#undef HS
    }
    __syncthreads();

    // ---- reduce 32 k-split partials -> gh (threads 0..191, p = row*2+b) ----
    // PP=37 (odd): lane l reads base l*37 -> distinct banks, conflict-free.
    if (tid < 192) {
      const float* p = part_s + (size_t)tid * PP;
      float s = 0.f;
#pragma unroll
      for (int j = 0; j < 32; j++) s += p[j];
      gh_s[tid] = s + bhh_s[tid >> 1];
    }
    __syncthreads();

    // ---- gates + h update (64 threads: u = tid&31, b = tid>>5) ----
    if (tid < 64) {
      int u = tid & 31, b = tid >> 5;
      float xr = xq_s[0 * 64 + b * 32 + u];
      float xz = xq_s[1 * 64 + b * 32 + u];
      float xn = xq_s[2 * 64 + b * 32 + u];
      float ghr = gh_s[(0 * 32 + u) * 2 + b];
      float ghz = gh_s[(1 * 32 + u) * 2 + b];
      float ghn = gh_s[(2 * 32 + u) * 2 + b];
      float rg = fast_sigmoid(xr + ghr);
      float zg = fast_sigmoid(xz + ghz);
      float ng = fast_tanh(xn + rg * ghn);
      float hn = (1.f - zg) * ng + zg * hprev;
      // fused payload+tag publish: single 8B store, fire-and-forget
      u32x2 pvs;
      pvs.x = __float_as_uint(hn);
      pvs.y = flag_base + (unsigned)t + 1u;
      unsigned* dst = mb + ((size_t)((t & 1) * GRP + g) * 1024
                            + (size_t)(m * 64 + b * 32 + u)) * 2;
      asm volatile("global_store_dwordx2 %0, %1, off sc0 sc1"
                   :: "v"(dst), "v"(pvs) : "memory");
      hprev = hn;
      // off-critical-path epilogue: GELU + out store
      float ov = hn;
      if (apply_gelu) ov = 0.5f * hn * (1.f + erff(hn * 0.70710678118654752f));
      out[((size_t)((b0 + b) * TLEN + t)) * KDIM + u0 + u] = ov;
    }
  }
}

// ---------------------------------------------------------------------------
// ws layout: [0, 402.65MB) xp_t | mailbox 128KB
// ---------------------------------------------------------------------------
extern "C" void kernel_launch(void* const* d_in, const int* in_sizes, int n_in,
                              void* d_out, int out_size, void* d_ws, size_t ws_size,
                              hipStream_t stream) {
  const float* x     = (const float*)d_in[0];
  const float* w_ih1 = (const float*)d_in[1];
  const float* w_hh1 = (const float*)d_in[2];
  const float* b_ih1 = (const float*)d_in[3];
  const float* b_hh1 = (const float*)d_in[4];
  const float* w_ih2 = (const float*)d_in[5];
  const float* w_hh2 = (const float*)d_in[6];
  const float* b_ih2 = (const float*)d_in[7];
  const float* b_hh2 = (const float*)d_in[8];
  float* y = (float*)d_out;

  char* ws = (char*)d_ws;
  const size_t XPB = (size_t)BATCH * TLEN * G3 * sizeof(float);
  float*    xp = (float*)ws;
  unsigned* mb = (unsigned*)(ws + XPB);

  hipFuncSetAttribute((const void*)gru_rec,
                      hipFuncAttributeMaxDynamicSharedMemorySize, SMEM_BYTES);
  // mailbox: 2 parities x 8 groups x 1024 pairs x 8B = 128 KiB
  hipMemsetAsync(mb, 0, (size_t)2 * GRP * UBK * 64 * 2 * sizeof(unsigned), stream);

  dim3 gg(12, 512), tb(256);
  const int M = BATCH * TLEN;

  gemm_nt_bias<<<gg, tb, 0, stream>>>(x, w_ih1, b_ih1, xp, M, G3);
  gru_rec<<<dim3(NBLK), REC_THREADS, SMEM_BYTES, stream>>>(xp, w_hh1, b_hh1, mb, 0u, y, 1);
  gemm_nt_bias<<<gg, tb, 0, stream>>>(y, w_ih2, b_ih2, xp, M, G3);
  gru_rec<<<dim3(NBLK), REC_THREADS, SMEM_BYTES, stream>>>(xp, w_hh2, b_hh2, mb, (unsigned)TLEN, y, 0);
}